// Round 1
// baseline (16024.657 us; speedup 1.0000x reference)
//
#include <hip/hip_runtime.h>

// LSTM: B=64, T=512, F=512, H=1024. fp32 in/out, bf16 MFMA compute.
// gates[b,n] at step t = sum_f x[b,t,f]U[f,n] + sum_k h[b,k]W[k,n] + bias[n]
// f,i,o,ct = sigmoid(gate quadrants); c = f*c + i*ct; h = o*tanh(c).

#define Bz 64
#define Tz 512
#define Fz 512
#define Hz 1024
#define NH 16   // hidden indices per block
#define NBLK (Hz / NH)  // 64 blocks

typedef unsigned short u16;
typedef __attribute__((ext_vector_type(8))) short bf16x8;
typedef __attribute__((ext_vector_type(4))) float f32x4;

__device__ __forceinline__ u16 f2bf(float f) {
    union { float f; unsigned u; } v; v.f = f;
    unsigned r = v.u + 0x7FFFu + ((v.u >> 16) & 1u);
    return (u16)(r >> 16);
}

__device__ __forceinline__ float fast_sigmoid(float x) {
    return 1.0f / (1.0f + __expf(-x));
}
__device__ __forceinline__ float fast_tanh(float x) {
    float e = __expf(2.0f * x);
    return 1.0f - 2.0f / (e + 1.0f);
}

// ---- prep kernels ----

// x [B][T][F] f32 -> bf16, same layout. 4 elems/thread.
__global__ __launch_bounds__(256) void conv_x_kernel(const float* __restrict__ x,
                                                     u16* __restrict__ xb) {
    size_t i = (size_t)blockIdx.x * 256 + threadIdx.x;
    float4 v = ((const float4*)x)[i];
    ushort4 o;
    o.x = f2bf(v.x); o.y = f2bf(v.y); o.z = f2bf(v.z); o.w = f2bf(v.w);
    ((ushort4*)xb)[i] = o;
}

// dst[n][k] = src[k][n] (bf16). K = 1<<logK rows of src have length N.
__global__ __launch_bounds__(256) void transpose_bf16_kernel(const float* __restrict__ src,
                                                             u16* __restrict__ dst,
                                                             int logK, int N) {
    size_t id = (size_t)blockIdx.x * 256 + threadIdx.x;
    int K = 1 << logK;
    int k = (int)(id & (size_t)(K - 1));
    int n = (int)(id >> logK);
    dst[id] = f2bf(src[(size_t)k * N + n]);
}

__global__ __launch_bounds__(256) void init_state_kernel(u16* __restrict__ hb,
                                                         float* __restrict__ c) {
    int i = blockIdx.x * 256 + threadIdx.x;  // 65536 total
    hb[i] = 0;
    c[i] = 0.0f;
}

// ---- recurrent step ----
// 64 blocks x 256 threads. Block nb owns hidden j in [nb*16, nb*16+16).
// Wave w (0..3) = gate w; computes gates[64 batch][16 cols] via MFMA,
// cols n = w*1024 + nb*16 + (lane&15). K = 512 (x@U) + 1024 (h@W).
__global__ __launch_bounds__(256) void lstm_step_kernel(
    const u16* __restrict__ xb,    // [B][T][F] bf16
    const u16* __restrict__ UT,    // [4096][512] bf16 (U^T)
    const u16* __restrict__ WT,    // [4096][1024] bf16 (W^T)
    const float* __restrict__ bias,// [4096]
    const u16* __restrict__ hin,   // [B][H] bf16
    u16* __restrict__ hout,        // [B][H] bf16
    float* __restrict__ c,         // [B][H] f32
    float* __restrict__ out,       // d_out: hidden_seq | h_T | c_T
    int t) {
    __shared__ float gbuf[4 * Bz * NH];  // 16 KB: [gate][batch][jj]

    const int tid = threadIdx.x;
    const int w = tid >> 6;   // wave id = gate id (0=f,1=i,2=o,3=ct)
    const int l = tid & 63;
    const int lr = l & 15;    // A-row-local / B-col-local
    const int lk = l >> 4;    // k-subgroup
    const int nb = blockIdx.x;
    const int jbase = nb * NH;
    const int n = w * Hz + jbase + lr;  // gate column in [0,4096)

    f32x4 acc[4];
#pragma unroll
    for (int mt = 0; mt < 4; ++mt) acc[mt] = (f32x4){0.f, 0.f, 0.f, 0.f};

    const u16* Ubase = UT + (size_t)n * Fz;
    const u16* Wbase = WT + (size_t)n * Hz;

    // x @ U part: K = 512
#pragma unroll 4
    for (int kb = 0; kb < Fz / 32; ++kb) {
        const int k = kb * 32 + lk * 8;
        bf16x8 bfrag = *(const bf16x8*)(Ubase + k);
#pragma unroll
        for (int mt = 0; mt < 4; ++mt) {
            const int m = mt * 16 + lr;
            bf16x8 afrag = *(const bf16x8*)(xb + ((size_t)m * Tz + t) * Fz + k);
            acc[mt] = __builtin_amdgcn_mfma_f32_16x16x32_bf16(afrag, bfrag, acc[mt], 0, 0, 0);
        }
    }
    // h @ W part: K = 1024
#pragma unroll 4
    for (int kb = 0; kb < Hz / 32; ++kb) {
        const int k = kb * 32 + lk * 8;
        bf16x8 bfrag = *(const bf16x8*)(Wbase + k);
#pragma unroll
        for (int mt = 0; mt < 4; ++mt) {
            const int m = mt * 16 + lr;
            bf16x8 afrag = *(const bf16x8*)(hin + (size_t)m * Hz + k);
            acc[mt] = __builtin_amdgcn_mfma_f32_16x16x32_bf16(afrag, bfrag, acc[mt], 0, 0, 0);
        }
    }

    // D[row][col]: col = lane&15 (=lr), row = (lane>>4)*4 + i. Stash to LDS.
    const float bv = bias[n];
#pragma unroll
    for (int mt = 0; mt < 4; ++mt) {
#pragma unroll
        for (int i = 0; i < 4; ++i) {
            const int m = mt * 16 + lk * 4 + i;  // batch row
            gbuf[w * (Bz * NH) + m * NH + lr] = acc[mt][i] + bv;
        }
    }
    __syncthreads();

    // elementwise update: 1024 (batch, jj) pairs, 4 per thread
#pragma unroll
    for (int q = tid; q < Bz * NH; q += 256) {
        const int m = q >> 4;   // batch
        const int jj = q & 15;
        const float fg = fast_sigmoid(gbuf[q]);
        const float ig = fast_sigmoid(gbuf[Bz * NH + q]);
        const float og = fast_sigmoid(gbuf[2 * Bz * NH + q]);
        const float ct = fast_sigmoid(gbuf[3 * Bz * NH + q]);  // faithful: sigmoid
        const int j = jbase + jj;
        const size_t ci = (size_t)m * Hz + j;
        const float cn = fg * c[ci] + ig * ct;
        c[ci] = cn;
        const float hn = og * fast_tanh(cn);
        hout[ci] = f2bf(hn);
        out[((size_t)m * Tz + t) * Hz + j] = hn;
        if (t == Tz - 1) {
            out[(size_t)Bz * Tz * Hz + ci] = hn;                     // h_T
            out[(size_t)Bz * Tz * Hz + (size_t)Bz * Hz + ci] = cn;   // c_T
        }
    }
}

extern "C" void kernel_launch(void* const* d_in, const int* in_sizes, int n_in,
                              void* d_out, int out_size, void* d_ws, size_t ws_size,
                              hipStream_t stream) {
    const float* x    = (const float*)d_in[0];  // [64][512][512]
    const float* U    = (const float*)d_in[1];  // [512][4096]
    const float* W    = (const float*)d_in[2];  // [1024][4096]
    const float* bias = (const float*)d_in[3];  // [4096]
    float* out = (float*)d_out;
    char* ws = (char*)d_ws;

    // ws layout (bytes):
    u16*   xb  = (u16*)(ws + 0);          // 64*512*512*2 = 33554432
    u16*   UT  = (u16*)(ws + 33554432);   // 4096*512*2   =  4194304
    u16*   WT  = (u16*)(ws + 37748736);   // 4096*1024*2  =  8388608
    u16*   hb0 = (u16*)(ws + 46137344);   // 64*1024*2    =   131072
    u16*   hb1 = (u16*)(ws + 46268416);   // 64*1024*2    =   131072
    float* c   = (float*)(ws + 46399488); // 64*1024*4    =   262144  (end ~44.5 MB)

    conv_x_kernel<<<16384, 256, 0, stream>>>(x, xb);                    // 16.7M elems /4
    transpose_bf16_kernel<<<8192, 256, 0, stream>>>(U, UT, 9, 4096);    // 2M elems
    transpose_bf16_kernel<<<16384, 256, 0, stream>>>(W, WT, 10, 4096);  // 4M elems
    init_state_kernel<<<256, 256, 0, stream>>>(hb0, c);

    for (int t = 0; t < Tz; ++t) {
        const u16* hin = (t & 1) ? hb1 : hb0;
        u16* hout      = (t & 1) ? hb0 : hb1;
        lstm_step_kernel<<<NBLK, 256, 0, stream>>>(xb, UT, WT, bias, hin, hout, c, out, t);
    }
}

// Round 3
// 2419.576 us; speedup vs baseline: 6.6229x; 6.6229x over previous
//
#include <hip/hip_runtime.h>

// Persistent LSTM: B=64, T=512, F=512, H=1024. fp32 in/out, bf16 MFMA compute.
// gates[b,n]_t = sum_f x[b,t,f]U[f,n] + sum_k h[b,k]W[k,n] + bias[n]
// Plain launch, 256 co-resident blocks (guaranteed by __launch_bounds__+LDS),
// per-batch-group atomic barriers, h exchanged via agent-scope (sc1) atomics.

#define Bz 64
#define Tz 512
#define Fz 512
#define Hz 1024
#define NKB 48           // (F+H)/32 MFMA k-steps
#define ROWP16 1544      // row stride in u16: 1536 + 8 pad
#define ROWP32 772       // row stride in u32
#define NBLK 256
#define NTHR 256

typedef unsigned short u16;
typedef unsigned int u32;
typedef __attribute__((ext_vector_type(8))) short bf16x8;
typedef __attribute__((ext_vector_type(4))) float f32x4;

__device__ __forceinline__ u16 f2bf(float f) {
    union { float f; unsigned u; } v; v.f = f;
    unsigned r = v.u + 0x7FFFu + ((v.u >> 16) & 1u);
    return (u16)(r >> 16);
}
__device__ __forceinline__ float fast_sigmoid(float x) {
    return 1.0f / (1.0f + __expf(-x));
}
__device__ __forceinline__ float fast_tanh(float x) {
    float e = __expf(2.0f * x);
    return 1.0f - 2.0f / (e + 1.0f);
}

// ---- prep kernels ----
__global__ __launch_bounds__(256) void conv_x_kernel(const float* __restrict__ x,
                                                     u16* __restrict__ xb) {
    size_t i = (size_t)blockIdx.x * 256 + threadIdx.x;
    float4 v = ((const float4*)x)[i];
    ushort4 o;
    o.x = f2bf(v.x); o.y = f2bf(v.y); o.z = f2bf(v.z); o.w = f2bf(v.w);
    ((ushort4*)xb)[i] = o;
}

// dst[n][k] = bf16(src[k][n]); LDS 32x32 tile, both sides coalesced.
__global__ __launch_bounds__(256) void transpose_tile_kernel(const float* __restrict__ src,
                                                             u16* __restrict__ dst,
                                                             int K, int N) {
    __shared__ u16 tile[32][33];
    const int ntk = K >> 5;
    const int tk = blockIdx.x % ntk;
    const int tn = blockIdx.x / ntk;
    const int c = threadIdx.x & 31;
    const int r0 = threadIdx.x >> 5;  // 0..7
#pragma unroll
    for (int rr = 0; rr < 32; rr += 8) {
        const int r = r0 + rr;
        tile[r][c] = f2bf(src[(size_t)(tk * 32 + r) * N + tn * 32 + c]);
    }
    __syncthreads();
#pragma unroll
    for (int rr = 0; rr < 32; rr += 8) {
        const int r = r0 + rr;
        dst[(size_t)(tn * 32 + r) * K + tk * 32 + c] = tile[c][r];
    }
}

__global__ __launch_bounds__(256) void init_state_kernel(u32* __restrict__ h0,
                                                         u32* __restrict__ bar) {
    int i = blockIdx.x * 256 + threadIdx.x;  // 32768 total
    h0[i] = 0u;
    if (i < 128) bar[i] = 0u;
}

// ---- persistent recurrent kernel ----
// Block (bg=blk>>6, jg=blk&63): batches [16bg,16bg+16), j in [16jg,16jg+16).
// Wave w = gate w (cols n = w*1024 + 16jg + lane&15); B-slice in 192 VGPRs.
__global__ __launch_bounds__(NTHR, 1) void lstm_persist(
    const u16* __restrict__ xb,    // [B][T][F] bf16
    const u16* __restrict__ UT,    // [4096][512] bf16
    const u16* __restrict__ WT,    // [4096][1024] bf16
    const float* __restrict__ bias,// [4096]
    u32* __restrict__ h0,          // [B][H/2] bf16-pairs (zeroed)
    u32* __restrict__ h1,
    float* __restrict__ out,       // hidden_seq | h_T | c_T
    u32* __restrict__ bar) {       // 4 counters, 128B apart

    __shared__ __align__(16) u16 albuf[16 * ROWP16];  // [x(512)|h(1024)|pad] x 16 rows
    __shared__ float gbuf[4 * 16 * 16];

    const int tid = threadIdx.x;
    const int w = tid >> 6;
    const int l = tid & 63;
    const int lr = l & 15;
    const int lk = l >> 4;
    const int bg = blockIdx.x >> 6;
    const int jg = blockIdx.x & 63;
    const int mbase = bg * 16;
    const int jbase = jg * 16;
    const int n = w * Hz + jbase + lr;

    // B operand resident in registers
    bf16x8 bw[NKB];
    {
        const u16* Ub = UT + (size_t)n * Fz + lk * 8;
        const u16* Wb = WT + (size_t)n * Hz + lk * 8;
#pragma unroll
        for (int kb = 0; kb < 16; ++kb) bw[kb] = *(const bf16x8*)(Ub + kb * 32);
#pragma unroll
        for (int kb = 0; kb < 32; ++kb) bw[16 + kb] = *(const bf16x8*)(Wb + kb * 32);
    }
    const float bv = bias[n];

    const int ml_e = tid >> 4;
    const int jj_e = tid & 15;
    const int m_e = mbase + ml_e;
    const int j_e = jbase + jj_e;
    float creg = 0.0f;

    const size_t OFF_HT = (size_t)Bz * Tz * Hz;
    const size_t OFF_CT = OFF_HT + (size_t)Bz * Hz;

    u32* __restrict__ barp = bar + bg * 32;  // 128B spacing
    unsigned target = 64;

#pragma unroll 1
    for (int t = 0; t < Tz; ++t) {
        u32* __restrict__ hin  = (t & 1) ? h1 : h0;
        u32* __restrict__ hout = (t & 1) ? h0 : h1;

        // ---- stage x_t (normal cached loads; 64x reuse across jg-blocks) ----
        {
            bf16x8 tx[4];
#pragma unroll
            for (int it = 0; it < 4; ++it) {
                int idx = it * NTHR + tid;
                int ml = idx >> 6, ci = idx & 63;
                tx[it] = *(const bf16x8*)(xb + ((size_t)(mbase + ml) * Tz + t) * Fz + ci * 8);
            }
#pragma unroll
            for (int it = 0; it < 4; ++it) {
                int idx = it * NTHR + tid;
                int ml = idx >> 6, ci = idx & 63;
                *(bf16x8*)(albuf + ml * ROWP16 + ci * 8) = tx[it];
            }
        }
        // ---- stage h (agent-scope coherent u32 loads; bypass stale L1/L2) ----
        {
            u32 hv[8];
            const u32* hsrc = hin + mbase * 512;
            u32* albuf32 = (u32*)albuf;
#pragma unroll
            for (int half = 0; half < 4; ++half) {
#pragma unroll
                for (int it = 0; it < 8; ++it) {
                    int idx = (half * 8 + it) * NTHR + tid;
                    hv[it] = __hip_atomic_load(hsrc + idx, __ATOMIC_RELAXED,
                                               __HIP_MEMORY_SCOPE_AGENT);
                }
#pragma unroll
                for (int it = 0; it < 8; ++it) {
                    int idx = (half * 8 + it) * NTHR + tid;
                    int ml = idx >> 9, ci = idx & 511;
                    albuf32[ml * ROWP32 + 256 + ci] = hv[it];
                }
            }
        }
        __syncthreads();

        // ---- 16x16 K=1536 MFMA ----
        f32x4 acc = (f32x4){0.f, 0.f, 0.f, 0.f};
        {
            const u16* abase = albuf + lr * ROWP16 + lk * 8;
#pragma unroll
            for (int kb = 0; kb < NKB; ++kb) {
                bf16x8 af = *(const bf16x8*)(abase + kb * 32);
                acc = __builtin_amdgcn_mfma_f32_16x16x32_bf16(af, bw[kb], acc, 0, 0, 0);
            }
        }

        // ---- gate exchange: D row=(lk*4+i)=batch, col=lr ----
#pragma unroll
        for (int i = 0; i < 4; ++i)
            gbuf[w * 256 + (lk * 4 + i) * 16 + lr] = acc[i] + bv;
        __syncthreads();

        // ---- elementwise update; h store via packed agent-scope u32 ----
        {
            float fg = fast_sigmoid(gbuf[tid]);
            float ig = fast_sigmoid(gbuf[256 + tid]);
            float og = fast_sigmoid(gbuf[512 + tid]);
            float ct = fast_sigmoid(gbuf[768 + tid]);  // faithful: sigmoid
            creg = fg * creg + ig * ct;
            float hn = og * fast_tanh(creg);
            out[((size_t)m_e * Tz + t) * Hz + j_e] = hn;
            if (t == Tz - 1) {
                out[OFF_HT + (size_t)m_e * Hz + j_e] = hn;
                out[OFF_CT + (size_t)m_e * Hz + j_e] = creg;
            }
            float hn_nb = __shfl_xor(hn, 1);  // partner jj^1 (same wave)
            if (!(jj_e & 1)) {
                u32 packed = ((u32)f2bf(hn_nb) << 16) | (u32)f2bf(hn);
                __hip_atomic_store(hout + m_e * 512 + (j_e >> 1), packed,
                                   __ATOMIC_RELAXED, __HIP_MEMORY_SCOPE_AGENT);
            }
        }

        // ---- per-bg barrier (skip after last step) ----
        if (t != Tz - 1) {
            __syncthreads();  // drains each wave's vmem (stores at LLC)
            if (tid == 0) {
                __hip_atomic_fetch_add(barp, 1u, __ATOMIC_RELAXED,
                                       __HIP_MEMORY_SCOPE_AGENT);
                while (__hip_atomic_load(barp, __ATOMIC_RELAXED,
                                         __HIP_MEMORY_SCOPE_AGENT) < target)
                    __builtin_amdgcn_s_sleep(2);
            }
            __syncthreads();
            target += 64;
        }
    }
}

extern "C" void kernel_launch(void* const* d_in, const int* in_sizes, int n_in,
                              void* d_out, int out_size, void* d_ws, size_t ws_size,
                              hipStream_t stream) {
    const float* x    = (const float*)d_in[0];  // [64][512][512]
    const float* U    = (const float*)d_in[1];  // [512][4096]
    const float* W    = (const float*)d_in[2];  // [1024][4096]
    const float* bias = (const float*)d_in[3];  // [4096]
    float* out = (float*)d_out;
    char* ws = (char*)d_ws;

    u16* xb  = (u16*)(ws + 0);          // 33,554,432 B
    u16* UT  = (u16*)(ws + 33554432);   //  4,194,304 B
    u16* WT  = (u16*)(ws + 37748736);   //  8,388,608 B
    u32* h0  = (u32*)(ws + 46137344);   //    131,072 B
    u32* h1  = (u32*)(ws + 46268416);   //    131,072 B
    u32* bar = (u32*)(ws + 46399488);   //        512 B

    conv_x_kernel<<<16384, 256, 0, stream>>>(x, xb);
    transpose_tile_kernel<<<2048, 256, 0, stream>>>(U, UT, 512, 4096);
    transpose_tile_kernel<<<4096, 256, 0, stream>>>(W, WT, 1024, 4096);
    init_state_kernel<<<128, 256, 0, stream>>>(h0, bar);

    lstm_persist<<<NBLK, NTHR, 0, stream>>>(xb, UT, WT, bias, h0, h1, out, bar);
}

// Round 6
// 1534.322 us; speedup vs baseline: 10.4441x; 1.5770x over previous
//
#include <hip/hip_runtime.h>

// Persistent LSTM: B=64, T=512, F=512, H=1024. fp32 in/out, bf16 MFMA compute.
// gates[b,n]_t = sum_f x[b,t,f]U[f,n] + sum_k h[b,k]W[k,n] + bias[n]
// 256 co-resident blocks; per-batch-group (64-wide) LLC atomic barriers;
// h exchanged via agent-scope atomics (u64 = 4 bf16); x.U MFMA hoisted
// before the barrier wait.

#define Bz 64
#define Tz 512
#define Fz 512
#define Hz 1024
#define ROWP16 1544      // LDS row stride in u16: 1536 + 8 pad
#define ROWP64 386       // same in u64
#define NBLK 256
#define NTHR 256

typedef unsigned short u16;
typedef unsigned int u32;
typedef unsigned long long u64;
typedef __attribute__((ext_vector_type(8))) short bf16x8;
typedef __attribute__((ext_vector_type(4))) float f32x4;

__device__ __forceinline__ u16 f2bf(float f) {
    union { float f; unsigned u; } v; v.f = f;
    unsigned r = v.u + 0x7FFFu + ((v.u >> 16) & 1u);
    return (u16)(r >> 16);
}
__device__ __forceinline__ float fast_sigmoid(float x) {
    return 1.0f / (1.0f + __expf(-x));
}
__device__ __forceinline__ float fast_tanh(float x) {
    float e = __expf(2.0f * x);
    return 1.0f - 2.0f / (e + 1.0f);
}

// ---- prep kernels ----
__global__ __launch_bounds__(256) void conv_x_kernel(const float* __restrict__ x,
                                                     u16* __restrict__ xb) {
    size_t i = (size_t)blockIdx.x * 256 + threadIdx.x;
    float4 v = ((const float4*)x)[i];
    ushort4 o;
    o.x = f2bf(v.x); o.y = f2bf(v.y); o.z = f2bf(v.z); o.w = f2bf(v.w);
    ((ushort4*)xb)[i] = o;
}

__global__ __launch_bounds__(256) void transpose_tile_kernel(const float* __restrict__ src,
                                                             u16* __restrict__ dst,
                                                             int K, int N) {
    __shared__ u16 tile[32][33];
    const int ntk = K >> 5;
    const int tk = blockIdx.x % ntk;
    const int tn = blockIdx.x / ntk;
    const int c = threadIdx.x & 31;
    const int r0 = threadIdx.x >> 5;
#pragma unroll
    for (int rr = 0; rr < 32; rr += 8) {
        const int r = r0 + rr;
        tile[r][c] = f2bf(src[(size_t)(tk * 32 + r) * N + tn * 32 + c]);
    }
    __syncthreads();
#pragma unroll
    for (int rr = 0; rr < 32; rr += 8) {
        const int r = r0 + rr;
        dst[(size_t)(tn * 32 + r) * K + tk * 32 + c] = tile[c][r];
    }
}

__global__ __launch_bounds__(256) void init_state_kernel(u32* __restrict__ h0,
                                                         u32* __restrict__ bar) {
    int i = blockIdx.x * 256 + threadIdx.x;  // 32768 total
    h0[i] = 0u;
    if (i < 128) bar[i] = 0u;
}

// ---- persistent recurrent kernel ----
// Block (bg=blk>>6, jg=blk&63): batches [16bg,16bg+16), j in [16jg,16jg+16).
// Wave w = gate w (cols n = w*1024 + 16jg + lane&15); B-slice in 192 VGPRs.
__global__ __launch_bounds__(NTHR, 1) void lstm_persist(
    const u16* __restrict__ xb,    // [B][T][F] bf16
    const u16* __restrict__ UT,    // [4096][512] bf16
    const u16* __restrict__ WT,    // [4096][1024] bf16
    const float* __restrict__ bias,// [4096]
    u64* __restrict__ h0,          // [B][256] bf16-quads (zeroed)
    u64* __restrict__ h1,
    float* __restrict__ out,       // hidden_seq | h_T | c_T
    u32* __restrict__ bar) {       // 4 counters, 128B apart

    __shared__ __align__(16) u16 albuf[16 * ROWP16];  // [x(512)|h(1024)|pad] x 16
    __shared__ float gbuf[4 * 16 * 16];

    const int tid = threadIdx.x;
    const int w = tid >> 6;
    const int l = tid & 63;
    const int lr = l & 15;
    const int lk = l >> 4;
    const int bg = blockIdx.x >> 6;
    const int jg = blockIdx.x & 63;
    const int mbase = bg * 16;
    const int jbase = jg * 16;
    const int n = w * Hz + jbase + lr;

    // B operand resident in registers
    bf16x8 bw[48];
    {
        const u16* Ub = UT + (size_t)n * Fz + lk * 8;
        const u16* Wb = WT + (size_t)n * Hz + lk * 8;
#pragma unroll
        for (int kb = 0; kb < 16; ++kb) bw[kb] = *(const bf16x8*)(Ub + kb * 32);
#pragma unroll
        for (int kb = 0; kb < 32; ++kb) bw[16 + kb] = *(const bf16x8*)(Wb + kb * 32);
    }
    const float bv = bias[n];

    const int ml_e = tid >> 4;
    const int jj_e = tid & 15;
    const int m_e = mbase + ml_e;
    const int j_e = jbase + jj_e;
    float creg = 0.0f;

    const size_t OFF_HT = (size_t)Bz * Tz * Hz;
    const size_t OFF_CT = OFF_HT + (size_t)Bz * Hz;

    u32* __restrict__ barp = bar + bg * 32;  // 128B spacing
    u64* albuf64 = (u64*)albuf;

    // prefetch x_0
    bf16x8 tx[4];
#pragma unroll
    for (int it = 0; it < 4; ++it) {
        int idx = it * NTHR + tid;
        int ml = idx >> 6, ci = idx & 63;
        tx[it] = *(const bf16x8*)(xb + ((size_t)(mbase + ml) * Tz + 0) * Fz + ci * 8);
    }

#pragma unroll 1
    for (int t = 0; t < Tz; ++t) {
        const u64* __restrict__ hin  = (t & 1) ? h1 : h0;
        u64* __restrict__ hout       = (t & 1) ? h0 : h1;

        // ---- A: prefetched x_t regs -> LDS ----
#pragma unroll
        for (int it = 0; it < 4; ++it) {
            int idx = it * NTHR + tid;
            int ml = idx >> 6, ci = idx & 63;
            *(bf16x8*)(albuf + ml * ROWP16 + ci * 8) = tx[it];
        }
        __syncthreads();

        // ---- D1: x.U MFMA (no h dependence) -- runs while others arrive ----
        f32x4 a0 = {0.f,0.f,0.f,0.f}, a1 = a0, a2 = a0, a3 = a0;
        {
            const u16* abase = albuf + lr * ROWP16 + lk * 8;
#pragma unroll
            for (int kb = 0; kb < 16; kb += 4) {
                a0 = __builtin_amdgcn_mfma_f32_16x16x32_bf16(*(const bf16x8*)(abase + (kb+0)*32), bw[kb+0], a0, 0,0,0);
                a1 = __builtin_amdgcn_mfma_f32_16x16x32_bf16(*(const bf16x8*)(abase + (kb+1)*32), bw[kb+1], a1, 0,0,0);
                a2 = __builtin_amdgcn_mfma_f32_16x16x32_bf16(*(const bf16x8*)(abase + (kb+2)*32), bw[kb+2], a2, 0,0,0);
                a3 = __builtin_amdgcn_mfma_f32_16x16x32_bf16(*(const bf16x8*)(abase + (kb+3)*32), bw[kb+3], a3, 0,0,0);
            }
        }

        // ---- barrier wait: h(t-1) from all jg-blocks of this bg published ----
        if (t) {
            if (tid == 0) {
                const unsigned tgt = (unsigned)t * 64u;
                while (__hip_atomic_load(barp, __ATOMIC_RELAXED,
                                         __HIP_MEMORY_SCOPE_AGENT) < tgt) { }
            }
            __syncthreads();
        }

        // ---- C: h tile = 16 rows x 256 u64; 16 outstanding b64 loads ----
        {
            u64 hv[16];
            const u64* hsrc = hin + (size_t)mbase * 256;
#pragma unroll
            for (int r = 0; r < 16; ++r)
                hv[r] = __hip_atomic_load(hsrc + r * NTHR + tid, __ATOMIC_RELAXED,
                                          __HIP_MEMORY_SCOPE_AGENT);
#pragma unroll
            for (int r = 0; r < 16; ++r) {
                int idx = r * NTHR + tid;
                int ml = idx >> 8, ci = idx & 255;   // 256 u64 per batch row
                albuf64[ml * ROWP64 + 128 + ci] = hv[r];  // 128 u64 = 512 u16 = x-section
            }
        }
        __syncthreads();

        // ---- D2: h.W MFMA ----
        {
            const u16* abase = albuf + lr * ROWP16 + 512 + lk * 8;
#pragma unroll
            for (int kb = 0; kb < 32; kb += 4) {
                a0 = __builtin_amdgcn_mfma_f32_16x16x32_bf16(*(const bf16x8*)(abase + (kb+0)*32), bw[16+kb+0], a0, 0,0,0);
                a1 = __builtin_amdgcn_mfma_f32_16x16x32_bf16(*(const bf16x8*)(abase + (kb+1)*32), bw[16+kb+1], a1, 0,0,0);
                a2 = __builtin_amdgcn_mfma_f32_16x16x32_bf16(*(const bf16x8*)(abase + (kb+2)*32), bw[16+kb+2], a2, 0,0,0);
                a3 = __builtin_amdgcn_mfma_f32_16x16x32_bf16(*(const bf16x8*)(abase + (kb+3)*32), bw[16+kb+3], a3, 0,0,0);
            }
        }
        f32x4 acc = (a0 + a1) + (a2 + a3);

        // ---- gate exchange: D row=(lk*4+i)=batch, col=lr ----
#pragma unroll
        for (int i = 0; i < 4; ++i)
            gbuf[w * 256 + (lk * 4 + i) * 16 + lr] = acc[i] + bv;
        __syncthreads();

        // ---- elementwise; h packed u64 agent-scope store ----
        float hn, cn;
        {
            float fg = fast_sigmoid(gbuf[tid]);
            float ig = fast_sigmoid(gbuf[256 + tid]);
            float og = fast_sigmoid(gbuf[512 + tid]);
            float ct = fast_sigmoid(gbuf[768 + tid]);  // faithful: sigmoid
            cn = fg * creg + ig * ct;
            creg = cn;
            hn = og * fast_tanh(cn);
            float hn1 = __shfl_xor(hn, 1);
            u32 p01 = ((u32)f2bf(hn1) << 16) | (u32)f2bf(hn);   // valid on even jj
            u32 p23 = __shfl_xor(p01, 2);                       // pair (jj+2,jj+3)
            if (!(jj_e & 3)) {
                u64 pk = ((u64)p23 << 32) | (u64)p01;
                __hip_atomic_store(hout + (size_t)m_e * 256 + (j_e >> 2), pk,
                                   __ATOMIC_RELAXED, __HIP_MEMORY_SCOPE_AGENT);
            }
        }

        // ---- release: drain stores, then arrive ----
        if (t != Tz - 1) {
            __syncthreads();  // implies s_waitcnt vmcnt(0): h stores visible
            if (tid == 0)
                __hip_atomic_fetch_add(barp, 1u, __ATOMIC_RELAXED,
                                       __HIP_MEMORY_SCOPE_AGENT);
        }

        // ---- off-critical-path: out stores + next x prefetch ----
        out[((size_t)m_e * Tz + t) * Hz + j_e] = hn;
        if (t == Tz - 1) {
            out[OFF_HT + (size_t)m_e * Hz + j_e] = hn;
            out[OFF_CT + (size_t)m_e * Hz + j_e] = cn;
        } else {
#pragma unroll
            for (int it = 0; it < 4; ++it) {
                int idx = it * NTHR + tid;
                int ml = idx >> 6, ci = idx & 63;
                tx[it] = *(const bf16x8*)(xb + ((size_t)(mbase + ml) * Tz + (t + 1)) * Fz + ci * 8);
            }
        }
    }
}

extern "C" void kernel_launch(void* const* d_in, const int* in_sizes, int n_in,
                              void* d_out, int out_size, void* d_ws, size_t ws_size,
                              hipStream_t stream) {
    const float* x    = (const float*)d_in[0];  // [64][512][512]
    const float* U    = (const float*)d_in[1];  // [512][4096]
    const float* W    = (const float*)d_in[2];  // [1024][4096]
    const float* bias = (const float*)d_in[3];  // [4096]
    float* out = (float*)d_out;
    char* ws = (char*)d_ws;

    u16* xb  = (u16*)(ws + 0);          // 33,554,432 B
    u16* UT  = (u16*)(ws + 33554432);   //  4,194,304 B
    u16* WT  = (u16*)(ws + 37748736);   //  8,388,608 B
    u64* h0  = (u64*)(ws + 46137344);   //    131,072 B
    u64* h1  = (u64*)(ws + 46268416);   //    131,072 B
    u32* bar = (u32*)(ws + 46399488);   //        512 B

    conv_x_kernel<<<16384, 256, 0, stream>>>(x, xb);
    transpose_tile_kernel<<<2048, 256, 0, stream>>>(U, UT, 512, 4096);
    transpose_tile_kernel<<<4096, 256, 0, stream>>>(W, WT, 1024, 4096);
    init_state_kernel<<<128, 256, 0, stream>>>((u32*)h0, bar);

    lstm_persist<<<NBLK, NTHR, 0, stream>>>(xb, UT, WT, bias, h0, h1, out, bar);
}